// Round 4
// baseline (917.507 us; speedup 1.0000x reference)
//
#include <hip/hip_runtime.h>
#include <cstdint>

typedef __attribute__((ext_vector_type(8))) short bf16x8;
typedef __attribute__((ext_vector_type(4))) float f32x4;

#define N_TOK    8192
#define DMODEL   1024
#define HDIM     4096
#define CAPACITY 2048

__device__ __forceinline__ unsigned short f2bf(float f) {
  unsigned u = __float_as_uint(f);
  u += 0x7FFFu + ((u >> 16) & 1u);
  return (unsigned short)(u >> 16);
}

// ---------------- x -> bf16 ----------------
__global__ void cvtx_kernel(const float* __restrict__ x, unsigned short* __restrict__ xb) {
  long i0 = ((long)blockIdx.x * 256 + threadIdx.x) * 16;
#pragma unroll
  for (int ii = 0; ii < 4; ii++) {
    float4 v = *(const float4*)(x + i0 + ii * 4);
    ushort4 u;
    u.x = f2bf(v.x); u.y = f2bf(v.y); u.z = f2bf(v.z); u.w = f2bf(v.w);
    *(ushort4*)(xb + i0 + ii * 4) = u;
  }
}

// ---------------- router: logits -> top2 ----------------
__global__ void router_kernel(const float* __restrict__ x, const float* __restrict__ rw,
                              const float* __restrict__ rb, int4* __restrict__ recs) {
  int wave = threadIdx.x >> 6;
  int lane = threadIdx.x & 63;
  int tok = blockIdx.x * 4 + wave;
  const float* xr = x + (long)tok * DMODEL;
  float s[8];
#pragma unroll
  for (int e = 0; e < 8; e++) s[e] = 0.f;
  for (int ii = 0; ii < DMODEL / 64; ii++) {
    int k = lane + 64 * ii;
    float xv = xr[k];
    const float* wr = rw + k * 8;
    float4 a = *(const float4*)wr;
    float4 b = *(const float4*)(wr + 4);
    s[0] += xv * a.x; s[1] += xv * a.y; s[2] += xv * a.z; s[3] += xv * a.w;
    s[4] += xv * b.x; s[5] += xv * b.y; s[6] += xv * b.z; s[7] += xv * b.w;
  }
#pragma unroll
  for (int m = 1; m < 64; m <<= 1) {
#pragma unroll
    for (int e = 0; e < 8; e++) s[e] += __shfl_xor(s[e], m);
  }
  if (lane == 0) {
#pragma unroll
    for (int e = 0; e < 8; e++) s[e] += rb[e];
    int b0 = 0; float v0 = s[0];
#pragma unroll
    for (int e = 1; e < 8; e++) if (s[e] > v0) { v0 = s[e]; b0 = e; }
    int b1 = -1; float v1 = 0.f;
#pragma unroll
    for (int e = 0; e < 8; e++) {
      if (e == b0) continue;
      if (b1 < 0 || s[e] > v1) { v1 = s[e]; b1 = e; }
    }
    float t0 = 1.f / (1.f + expf(v1 - v0));
    float t1 = 1.f - t0;
    recs[tok] = make_int4(b0, b1, __float_as_int(t0), __float_as_int(t1));
  }
}

// ---------------- capacity assignment (single block) ----------------
__device__ __forceinline__ int bump16(uint4& v, int e) {
  unsigned sh = (e & 1) ? 16u : 0u;
  unsigned inc = 1u << sh;
  unsigned old;
  switch (e >> 1) {
    case 0: old = v.x; v.x += inc; break;
    case 1: old = v.y; v.y += inc; break;
    case 2: old = v.z; v.z += inc; break;
    default: old = v.w; v.w += inc; break;
  }
  return (int)((old >> sh) & 0xFFFFu);
}

__device__ __forceinline__ unsigned field16(uint4 v, int e) {
  unsigned w;
  switch (e >> 1) { case 0: w = v.x; break; case 1: w = v.y; break; case 2: w = v.z; break; default: w = v.w; break; }
  return (w >> ((e & 1) ? 16 : 0)) & 0xFFFFu;
}

__global__ void assign_kernel(const int4* __restrict__ recs, int* __restrict__ buf,
                              float* __restrict__ wc, int* __restrict__ cnt,
                              float* __restrict__ auxOut) {
  __shared__ uint4 sc[1024];
  __shared__ unsigned sco[1024];
  __shared__ float pnum[8];
  int tid = threadIdx.x;
  if (tid < 8) pnum[tid] = 0.f;
  int4 rc[8];
#pragma unroll
  for (int i = 0; i < 8; i++) {
    rc[i] = recs[tid * 8 + i];
    rc[i].x &= 7; rc[i].y &= 7;
  }
  uint4 c; c.x = c.y = c.z = c.w = 0u;
#pragma unroll
  for (int i = 0; i < 8; i++) { bump16(c, rc[i].x); bump16(c, rc[i].y); }
  sc[tid] = c;
  __syncthreads();
  for (int off = 1; off < 1024; off <<= 1) {
    uint4 v; v.x = v.y = v.z = v.w = 0u;
    if (tid >= off) v = sc[tid - off];
    __syncthreads();
    sc[tid].x += v.x; sc[tid].y += v.y; sc[tid].z += v.z; sc[tid].w += v.w;
    __syncthreads();
  }
  uint4 base; base.x = base.y = base.z = base.w = 0u;
  if (tid > 0) base = sc[tid - 1];
  uint4 totals = sc[1023];

  uint4 run = base;
  float wof[8];
  unsigned oc = 0;
#pragma unroll
  for (int i = 0; i < 8; i++) {
    int tk = tid * 8 + i;
    int e0 = rc[i].x, e1 = rc[i].y;
    float w0 = __int_as_float(rc[i].z);
    float w1 = __int_as_float(rc[i].w);
    float w = 0.f;
    int r0 = bump16(run, e0);
    if (r0 < CAPACITY) {
      buf[e0 * CAPACITY + r0] = tk;
      wc[e0 * CAPACITY + r0] = w0;
      atomicAdd(&pnum[e0], w0);
    } else w += w0;
    int r1 = bump16(run, e1);
    if (r1 < CAPACITY) {
      buf[e1 * CAPACITY + r1] = tk;
      wc[e1 * CAPACITY + r1] = w1;
      atomicAdd(&pnum[e1], w1);
    } else w += w1;
    wof[i] = w;
    if (w > 0.f) oc++;
  }
  sco[tid] = oc;
  __syncthreads();
  for (int off = 1; off < 1024; off <<= 1) {
    unsigned v = (tid >= off) ? sco[tid - off] : 0u;
    __syncthreads();
    sco[tid] += v;
    __syncthreads();
  }
  unsigned ob = (tid > 0) ? sco[tid - 1] : 0u;
  unsigned Ot = sco[1023];
#pragma unroll
  for (int i = 0; i < 8; i++) {
    if (wof[i] > 0.f) {
      unsigned slot = ob++;
      int ve = 8 + (int)(slot >> 11);
      buf[ve * CAPACITY + (int)(slot & 2047)] = tid * 8 + i;
      wc[ve * CAPACITY + (int)(slot & 2047)] = wof[i];
    }
  }
  __syncthreads();
  if (tid == 0) {
    float aux = 0.f;
#pragma unroll
    for (int e = 0; e < 8; e++) {
      int tot = (int)field16(totals, e);
      int c2 = tot < CAPACITY ? tot : CAPACITY;
      cnt[e] = c2;
      float f = (float)c2 / (float)N_TOK;
      float p = pnum[e] / (float)(c2 > 1 ? c2 : 1);
      aux += f * p;
    }
#pragma unroll
    for (int i = 0; i < 4; i++) {
      int c2 = (int)Ot - i * CAPACITY;
      c2 = c2 < 0 ? 0 : (c2 > CAPACITY ? CAPACITY : c2);
      cnt[8 + i] = c2;
    }
    auxOut[0] = 0.01f * 8.f * aux;
  }
}

// ---------------- fp32 -> bf16 transpose of weight pairs ----------------
// pair p: mat1 = (p<8 ? w1[p] : ow1)  (DMODEL x HDIM)  -> wt1 slot p  (HDIM x DMODEL)
//         mat2 = (p<8 ? w2[p] : ow2)  (HDIM x DMODEL)  -> wt2 slot p  (DMODEL x HDIM)
// 2048 blocks per pair (1024 tiles each matrix).
__global__ __launch_bounds__(256) void transpose_all(
    const float* __restrict__ w1, const float* __restrict__ w2,
    const float* __restrict__ ow1, const float* __restrict__ ow2,
    unsigned short* __restrict__ wt1, unsigned short* __restrict__ wt2,
    long slotStride, int pairBase) {
  int pair = pairBase + blockIdx.x / 2048;
  int t = blockIdx.x & 2047;
  long srcOff = (long)pair * DMODEL * HDIM;
  long dstOff = (long)(blockIdx.x / 2048) * slotStride;
  const float* in; unsigned short* out; int R, C;
  if (t < 1024) {
    in = (pair < 8) ? w1 + srcOff : ow1;
    out = wt1 + dstOff;
    R = DMODEL; C = HDIM;
  } else {
    in = (pair < 8) ? w2 + srcOff : ow2;
    out = wt2 + dstOff;
    R = HDIM; C = DMODEL;
    t -= 1024;
  }
  int tr = t / (C >> 6);
  int tc = t % (C >> 6);
  int r0 = tr << 6, c0 = tc << 6;
  __shared__ float tl[64][65];
  int row = threadIdx.x >> 4, cg = threadIdx.x & 15;
#pragma unroll
  for (int i = 0; i < 4; i++) {
    int r = row + 16 * i;
    float4 v = *(const float4*)(in + (long)(r0 + r) * C + c0 + cg * 4);
    tl[r][cg * 4 + 0] = v.x; tl[r][cg * 4 + 1] = v.y;
    tl[r][cg * 4 + 2] = v.z; tl[r][cg * 4 + 3] = v.w;
  }
  __syncthreads();
#pragma unroll
  for (int i = 0; i < 4; i++) {
    int oc = row + 16 * i;
    ushort4 o;
    o.x = f2bf(tl[cg * 4 + 0][oc]);
    o.y = f2bf(tl[cg * 4 + 1][oc]);
    o.z = f2bf(tl[cg * 4 + 2][oc]);
    o.w = f2bf(tl[cg * 4 + 3][oc]);
    *(ushort4*)(out + (long)(c0 + oc) * R + r0 + cg * 4) = o;
  }
}

// ---------------- GEMM1: h[e] = relu(gather(xb) @ W1[e] + b1[e]) ----------------
// grid = nE * 512 (128x128 tiles; 16 mb x 32 nb; consecutive ids share the A-panel)
__global__ __launch_bounds__(256) void gemm1_kernel(
    const unsigned short* __restrict__ xb, const int* __restrict__ buf,
    const int* __restrict__ cnt, const unsigned short* __restrict__ wt1, long wtStride,
    const float* __restrict__ b1, const float* __restrict__ ob1,
    unsigned short* __restrict__ h, long hStride, int eBase) {
  int q = gridDim.x >> 3;
  int bx = blockIdx.x;
  int id = (bx & 7) * q + (bx >> 3);          // bijective XCD swizzle
  int e = eBase + (id >> 9);
  int rem = id & 511;
  int mb = rem >> 5, nb = rem & 31;
  int m0 = mb * 128, n0 = nb * 128;
  if (m0 >= cnt[e]) return;
  const int* bufe = buf + e * CAPACITY;
  int slot = e < 8 ? e : 8;
  const unsigned short* wte = wt1 + (long)slot * wtStride;
  const float* bias = (e < 8) ? b1 + (long)e * HDIM : ob1;
  unsigned short* he = h + (long)e * hStride;

  __shared__ unsigned short As[128 * 64];
  __shared__ unsigned short Bs[128 * 64];

  int tid = threadIdx.x;
  int rb8 = tid >> 3, ch = tid & 7;
  int tokA[4];
#pragma unroll
  for (int i = 0; i < 4; i++) tokA[i] = bufe[m0 + rb8 + 32 * i];

  int wave = tid >> 6, lane = tid & 63;
  int l15 = lane & 15, hi = lane >> 4;
  int mo = (wave >> 1) * 64, no = (wave & 1) * 64;

  f32x4 zero4 = {0.f, 0.f, 0.f, 0.f};
  f32x4 acc[4][4];
#pragma unroll
  for (int mi = 0; mi < 4; mi++)
#pragma unroll
    for (int ni = 0; ni < 4; ni++) acc[mi][ni] = zero4;

  for (int k0 = 0; k0 < DMODEL; k0 += 64) {
#pragma unroll
    for (int i = 0; i < 4; i++) {
      int r = rb8 + 32 * i;
      uint4 va; va.x = va.y = va.z = va.w = 0u;
      if ((unsigned)tokA[i] < (unsigned)N_TOK)
        va = *(const uint4*)(xb + (long)tokA[i] * DMODEL + k0 + ch * 8);
      *(uint4*)&As[r * 64 + ((ch ^ (r & 7)) << 3)] = va;
      uint4 vb = *(const uint4*)(wte + (long)(n0 + r) * DMODEL + k0 + ch * 8);
      *(uint4*)&Bs[r * 64 + ((ch ^ (r & 7)) << 3)] = vb;
    }
    __syncthreads();
#pragma unroll
    for (int ks = 0; ks < 2; ks++) {
      bf16x8 af[4], bfr[4];
#pragma unroll
      for (int mi = 0; mi < 4; mi++) {
        int r = mo + mi * 16 + l15;
        af[mi] = *(bf16x8*)&As[r * 64 + (((ks * 4 + hi) ^ (r & 7)) << 3)];
      }
#pragma unroll
      for (int ni = 0; ni < 4; ni++) {
        int r = no + ni * 16 + l15;
        bfr[ni] = *(bf16x8*)&Bs[r * 64 + (((ks * 4 + hi) ^ (r & 7)) << 3)];
      }
#pragma unroll
      for (int mi = 0; mi < 4; mi++)
#pragma unroll
        for (int ni = 0; ni < 4; ni++)
          acc[mi][ni] = __builtin_amdgcn_mfma_f32_16x16x32_bf16(af[mi], bfr[ni], acc[mi][ni], 0, 0, 0);
    }
    __syncthreads();
  }
#pragma unroll
  for (int ni = 0; ni < 4; ni++) {
    int col = n0 + no + ni * 16 + l15;
    float bv = bias[col];
#pragma unroll
    for (int mi = 0; mi < 4; mi++) {
#pragma unroll
      for (int j = 0; j < 4; j++) {
        int mr = m0 + mo + mi * 16 + hi * 4 + j;
        float val = acc[mi][ni][j] + bv;
        val = val > 0.f ? val : 0.f;
        he[(long)mr * HDIM + col] = f2bf(val);
      }
    }
  }
}

// ---------------- GEMM2: out[tok] += wc * (h[e] @ W2[e] + b2[e]) ----------------
// grid = nE * 128 * ksplit
__global__ __launch_bounds__(256) void gemm2_kernel(
    const unsigned short* __restrict__ h, long hStride,
    const unsigned short* __restrict__ wt2, long wtStride,
    const float* __restrict__ b2, const float* __restrict__ ob2,
    const int* __restrict__ buf, const float* __restrict__ wc,
    const int* __restrict__ cnt, float* __restrict__ out,
    int eBase, int per, int klen) {
  int q = gridDim.x >> 3;
  int bx = blockIdx.x;
  int id = (bx & 7) * q + (bx >> 3);          // bijective XCD swizzle
  int e = eBase + id / per;
  int rem = id % per;
  int tile = rem & 127;
  int kc = rem >> 7;
  int mb = tile >> 3, nb = tile & 7;
  int m0 = mb * 128, n0 = nb * 128;
  if (m0 >= cnt[e]) return;
  const int* bufe = buf + e * CAPACITY;
  const float* wce = wc + e * CAPACITY;
  int slot = e < 8 ? e : 8;
  const unsigned short* wte = wt2 + (long)slot * wtStride;
  const float* bias = (e < 8) ? b2 + (long)e * DMODEL : ob2;
  const unsigned short* he = h + (long)e * hStride;
  int kbase = kc * klen;

  __shared__ unsigned short As[128 * 64];
  __shared__ unsigned short Bs[128 * 64];

  int tid = threadIdx.x;
  int rb8 = tid >> 3, ch = tid & 7;
  int wave = tid >> 6, lane = tid & 63;
  int l15 = lane & 15, hi = lane >> 4;
  int mo = (wave >> 1) * 64, no = (wave & 1) * 64;

  f32x4 zero4 = {0.f, 0.f, 0.f, 0.f};
  f32x4 acc[4][4];
#pragma unroll
  for (int mi = 0; mi < 4; mi++)
#pragma unroll
    for (int ni = 0; ni < 4; ni++) acc[mi][ni] = zero4;

  for (int k0 = kbase; k0 < kbase + klen; k0 += 64) {
#pragma unroll
    for (int i = 0; i < 4; i++) {
      int r = rb8 + 32 * i;
      uint4 va = *(const uint4*)(he + (long)(m0 + r) * HDIM + k0 + ch * 8);
      *(uint4*)&As[r * 64 + ((ch ^ (r & 7)) << 3)] = va;
      uint4 vb = *(const uint4*)(wte + (long)(n0 + r) * HDIM + k0 + ch * 8);
      *(uint4*)&Bs[r * 64 + ((ch ^ (r & 7)) << 3)] = vb;
    }
    __syncthreads();
#pragma unroll
    for (int ks = 0; ks < 2; ks++) {
      bf16x8 af[4], bfr[4];
#pragma unroll
      for (int mi = 0; mi < 4; mi++) {
        int r = mo + mi * 16 + l15;
        af[mi] = *(bf16x8*)&As[r * 64 + (((ks * 4 + hi) ^ (r & 7)) << 3)];
      }
#pragma unroll
      for (int ni = 0; ni < 4; ni++) {
        int r = no + ni * 16 + l15;
        bfr[ni] = *(bf16x8*)&Bs[r * 64 + (((ks * 4 + hi) ^ (r & 7)) << 3)];
      }
#pragma unroll
      for (int mi = 0; mi < 4; mi++)
#pragma unroll
        for (int ni = 0; ni < 4; ni++)
          acc[mi][ni] = __builtin_amdgcn_mfma_f32_16x16x32_bf16(af[mi], bfr[ni], acc[mi][ni], 0, 0, 0);
    }
    __syncthreads();
  }
  float bcol[4];
#pragma unroll
  for (int ni = 0; ni < 4; ni++)
    bcol[ni] = (kc == 0) ? bias[n0 + no + ni * 16 + l15] : 0.f;
#pragma unroll
  for (int mi = 0; mi < 4; mi++) {
#pragma unroll
    for (int j = 0; j < 4; j++) {
      int m = m0 + mo + mi * 16 + hi * 4 + j;
      int t = bufe[m];
      if ((unsigned)t >= (unsigned)N_TOK) continue;
      float wv = wce[m];
      float* orow = out + (long)t * DMODEL;
#pragma unroll
      for (int ni = 0; ni < 4; ni++) {
        int col = n0 + no + ni * 16 + l15;
        float val = wv * (acc[mi][ni][j] + bcol[ni]);
        atomicAdd(orow + col, val);
      }
    }
  }
}

// ---------------- host ----------------
extern "C" void kernel_launch(void* const* d_in, const int* in_sizes, int n_in,
                              void* d_out, int out_size, void* d_ws, size_t ws_size,
                              hipStream_t stream) {
  const float* x   = (const float*)d_in[0];
  const float* rw  = (const float*)d_in[1];
  const float* rb  = (const float*)d_in[2];
  const float* w1  = (const float*)d_in[3];
  const float* b1  = (const float*)d_in[4];
  const float* w2  = (const float*)d_in[5];
  const float* b2  = (const float*)d_in[6];
  const float* ow1 = (const float*)d_in[7];
  const float* ob1 = (const float*)d_in[8];
  const float* ow2 = (const float*)d_in[9];
  const float* ob2 = (const float*)d_in[10];
  float* out = (float*)d_out;

  const long WSLOT = (long)DMODEL * HDIM;      // 4,194,304 elems (8 MB bf16)
  const long HSLOT = (long)CAPACITY * HDIM;    // 8,388,608 elems (16 MB bf16)

  // Fused layout needs: 1MB control + 16MB xb + 72MB wt1 + 72MB wt2 + 192MB h = ~354MB
  bool fused = ws_size >= 380ull * 1024 * 1024;

  char* ws = (char*)d_ws;
  int4* recs = (int4*)(ws);
  int*  buf  = (int*)(ws + 131072);
  float* wcp = (float*)(ws + 229376);
  int*  cnt  = (int*)(ws + 327680);
  unsigned short* xb  = (unsigned short*)(ws + 1048576);    // 16 MB
  unsigned short* wt1 = (unsigned short*)(ws + 17825792);
  unsigned short* wt2;
  unsigned short* h;
  if (fused) {
    wt2 = (unsigned short*)(ws + 93323264);    // wt1 + 9*8MB
    h   = (unsigned short*)(ws + 168820736);   // wt2 + 9*8MB; h = 12*16MB -> end ~353MB
  } else {
    wt2 = (unsigned short*)(ws + 26214400);    // wt1 + 8MB
    h   = (unsigned short*)(ws + 34603008);    // wt2 + 8MB; end ~49MB
  }

  hipMemsetAsync(d_out, 0, (size_t)out_size * sizeof(float), stream);
  hipMemsetAsync(buf, 0xFF, 12 * CAPACITY * sizeof(int), stream);
  hipMemsetAsync(wcp, 0, 12 * CAPACITY * sizeof(float), stream);

  cvtx_kernel<<<2048, 256, 0, stream>>>(x, xb);
  router_kernel<<<2048, 256, 0, stream>>>(x, rw, rb, recs);
  assign_kernel<<<1, 1024, 0, stream>>>(recs, buf, wcp, cnt, out + (long)N_TOK * DMODEL);

  if (fused) {
    transpose_all<<<9 * 2048, 256, 0, stream>>>(w1, w2, ow1, ow2, wt1, wt2, WSLOT, 0);
    gemm1_kernel<<<12 * 512, 256, 0, stream>>>(xb, buf, cnt, wt1, WSLOT, b1, ob1, h, HSLOT, 0);
    gemm2_kernel<<<12 * 128, 256, 0, stream>>>(h, HSLOT, wt2, WSLOT, b2, ob2, buf, wcp, cnt, out,
                                               0, 128, HDIM);
  } else {
    for (int e = 0; e < 12; e++) {
      if (e <= 8)
        transpose_all<<<2048, 256, 0, stream>>>(w1, w2, ow1, ow2, wt1, wt2, 0, e);
      gemm1_kernel<<<512, 256, 0, stream>>>(xb, buf, cnt, wt1, 0, b1, ob1, h, 0, e);
      gemm2_kernel<<<512, 256, 0, stream>>>(h, 0, wt2, 0, b2, ob2, buf, wcp, cnt, out,
                                            e, 512, HDIM / 4);
    }
  }
}

// Round 5
// 685.198 us; speedup vs baseline: 1.3390x; 1.3390x over previous
//
#include <hip/hip_runtime.h>
#include <cstdint>

typedef __attribute__((ext_vector_type(8))) short bf16x8;
typedef __attribute__((ext_vector_type(4))) float f32x4;

#define N_TOK    8192
#define DMODEL   1024
#define HDIM     4096
#define CAPACITY 2048

__device__ __forceinline__ unsigned short f2bf(float f) {
  unsigned u = __float_as_uint(f);
  u += 0x7FFFu + ((u >> 16) & 1u);
  return (unsigned short)(u >> 16);
}

// global (16B/lane) -> LDS direct DMA; lds base must be wave-uniform.
__device__ __forceinline__ void gl_lds16(const unsigned short* g, unsigned short* l) {
  __builtin_amdgcn_global_load_lds(
      (const __attribute__((address_space(1))) void*)g,
      (__attribute__((address_space(3))) void*)l, 16, 0, 0);
}

// ---------------- x -> bf16 ----------------
__global__ void cvtx_kernel(const float* __restrict__ x, unsigned short* __restrict__ xb) {
  long i0 = ((long)blockIdx.x * 256 + threadIdx.x) * 16;
#pragma unroll
  for (int ii = 0; ii < 4; ii++) {
    float4 v = *(const float4*)(x + i0 + ii * 4);
    ushort4 u;
    u.x = f2bf(v.x); u.y = f2bf(v.y); u.z = f2bf(v.z); u.w = f2bf(v.w);
    *(ushort4*)(xb + i0 + ii * 4) = u;
  }
}

// ---------------- router: logits -> top2 ----------------
__global__ void router_kernel(const float* __restrict__ x, const float* __restrict__ rw,
                              const float* __restrict__ rb, int4* __restrict__ recs) {
  int wave = threadIdx.x >> 6;
  int lane = threadIdx.x & 63;
  int tok = blockIdx.x * 4 + wave;
  const float* xr = x + (long)tok * DMODEL;
  float s[8];
#pragma unroll
  for (int e = 0; e < 8; e++) s[e] = 0.f;
  for (int ii = 0; ii < DMODEL / 64; ii++) {
    int k = lane + 64 * ii;
    float xv = xr[k];
    const float* wr = rw + k * 8;
    float4 a = *(const float4*)wr;
    float4 b = *(const float4*)(wr + 4);
    s[0] += xv * a.x; s[1] += xv * a.y; s[2] += xv * a.z; s[3] += xv * a.w;
    s[4] += xv * b.x; s[5] += xv * b.y; s[6] += xv * b.z; s[7] += xv * b.w;
  }
#pragma unroll
  for (int m = 1; m < 64; m <<= 1) {
#pragma unroll
    for (int e = 0; e < 8; e++) s[e] += __shfl_xor(s[e], m);
  }
  if (lane == 0) {
#pragma unroll
    for (int e = 0; e < 8; e++) s[e] += rb[e];
    int b0 = 0; float v0 = s[0];
#pragma unroll
    for (int e = 1; e < 8; e++) if (s[e] > v0) { v0 = s[e]; b0 = e; }
    int b1 = -1; float v1 = 0.f;
#pragma unroll
    for (int e = 0; e < 8; e++) {
      if (e == b0) continue;
      if (b1 < 0 || s[e] > v1) { v1 = s[e]; b1 = e; }
    }
    float t0 = 1.f / (1.f + expf(v1 - v0));
    float t1 = 1.f - t0;
    recs[tok] = make_int4(b0, b1, __float_as_int(t0), __float_as_int(t1));
  }
}

// ---------------- capacity assignment (single block) ----------------
__device__ __forceinline__ int bump16(uint4& v, int e) {
  unsigned sh = (e & 1) ? 16u : 0u;
  unsigned inc = 1u << sh;
  unsigned old;
  switch (e >> 1) {
    case 0: old = v.x; v.x += inc; break;
    case 1: old = v.y; v.y += inc; break;
    case 2: old = v.z; v.z += inc; break;
    default: old = v.w; v.w += inc; break;
  }
  return (int)((old >> sh) & 0xFFFFu);
}

__device__ __forceinline__ unsigned field16(uint4 v, int e) {
  unsigned w;
  switch (e >> 1) { case 0: w = v.x; break; case 1: w = v.y; break; case 2: w = v.z; break; default: w = v.w; break; }
  return (w >> ((e & 1) ? 16 : 0)) & 0xFFFFu;
}

__global__ void assign_kernel(const int4* __restrict__ recs, int* __restrict__ buf,
                              float* __restrict__ wc, int* __restrict__ cnt,
                              float* __restrict__ auxOut) {
  __shared__ uint4 sc[1024];
  __shared__ unsigned sco[1024];
  __shared__ float pnum[8];
  int tid = threadIdx.x;
  if (tid < 8) pnum[tid] = 0.f;
  int4 rc[8];
#pragma unroll
  for (int i = 0; i < 8; i++) {
    rc[i] = recs[tid * 8 + i];
    rc[i].x &= 7; rc[i].y &= 7;
  }
  uint4 c; c.x = c.y = c.z = c.w = 0u;
#pragma unroll
  for (int i = 0; i < 8; i++) { bump16(c, rc[i].x); bump16(c, rc[i].y); }
  sc[tid] = c;
  __syncthreads();
  for (int off = 1; off < 1024; off <<= 1) {
    uint4 v; v.x = v.y = v.z = v.w = 0u;
    if (tid >= off) v = sc[tid - off];
    __syncthreads();
    sc[tid].x += v.x; sc[tid].y += v.y; sc[tid].z += v.z; sc[tid].w += v.w;
    __syncthreads();
  }
  uint4 base; base.x = base.y = base.z = base.w = 0u;
  if (tid > 0) base = sc[tid - 1];
  uint4 totals = sc[1023];

  uint4 run = base;
  float wof[8];
  unsigned oc = 0;
#pragma unroll
  for (int i = 0; i < 8; i++) {
    int tk = tid * 8 + i;
    int e0 = rc[i].x, e1 = rc[i].y;
    float w0 = __int_as_float(rc[i].z);
    float w1 = __int_as_float(rc[i].w);
    float w = 0.f;
    int r0 = bump16(run, e0);
    if (r0 < CAPACITY) {
      buf[e0 * CAPACITY + r0] = tk;
      wc[e0 * CAPACITY + r0] = w0;
      atomicAdd(&pnum[e0], w0);
    } else w += w0;
    int r1 = bump16(run, e1);
    if (r1 < CAPACITY) {
      buf[e1 * CAPACITY + r1] = tk;
      wc[e1 * CAPACITY + r1] = w1;
      atomicAdd(&pnum[e1], w1);
    } else w += w1;
    wof[i] = w;
    if (w > 0.f) oc++;
  }
  sco[tid] = oc;
  __syncthreads();
  for (int off = 1; off < 1024; off <<= 1) {
    unsigned v = (tid >= off) ? sco[tid - off] : 0u;
    __syncthreads();
    sco[tid] += v;
    __syncthreads();
  }
  unsigned ob = (tid > 0) ? sco[tid - 1] : 0u;
  unsigned Ot = sco[1023];
#pragma unroll
  for (int i = 0; i < 8; i++) {
    if (wof[i] > 0.f) {
      unsigned slot = ob++;
      int ve = 8 + (int)(slot >> 11);
      buf[ve * CAPACITY + (int)(slot & 2047)] = tid * 8 + i;
      wc[ve * CAPACITY + (int)(slot & 2047)] = wof[i];
    }
  }
  __syncthreads();
  if (tid == 0) {
    float aux = 0.f;
#pragma unroll
    for (int e = 0; e < 8; e++) {
      int tot = (int)field16(totals, e);
      int c2 = tot < CAPACITY ? tot : CAPACITY;
      cnt[e] = c2;
      float f = (float)c2 / (float)N_TOK;
      float p = pnum[e] / (float)(c2 > 1 ? c2 : 1);
      aux += f * p;
    }
#pragma unroll
    for (int i = 0; i < 4; i++) {
      int c2 = (int)Ot - i * CAPACITY;
      c2 = c2 < 0 ? 0 : (c2 > CAPACITY ? CAPACITY : c2);
      cnt[8 + i] = c2;
    }
    auxOut[0] = 0.01f * 8.f * aux;
  }
}

// ---------------- fp32 -> bf16 transpose of weight pairs ----------------
__global__ __launch_bounds__(256) void transpose_all(
    const float* __restrict__ w1, const float* __restrict__ w2,
    const float* __restrict__ ow1, const float* __restrict__ ow2,
    unsigned short* __restrict__ wt1, unsigned short* __restrict__ wt2,
    long slotStride, int pairBase) {
  int pair = pairBase + blockIdx.x / 2048;
  int t = blockIdx.x & 2047;
  long srcOff = (long)pair * DMODEL * HDIM;
  long dstOff = (long)(blockIdx.x / 2048) * slotStride;
  const float* in; unsigned short* out; int R, C;
  if (t < 1024) {
    in = (pair < 8) ? w1 + srcOff : ow1;
    out = wt1 + dstOff;
    R = DMODEL; C = HDIM;
  } else {
    in = (pair < 8) ? w2 + srcOff : ow2;
    out = wt2 + dstOff;
    R = HDIM; C = DMODEL;
    t -= 1024;
  }
  int tr = t / (C >> 6);
  int tc = t % (C >> 6);
  int r0 = tr << 6, c0 = tc << 6;
  __shared__ float tl[64][65];
  int row = threadIdx.x >> 4, cg = threadIdx.x & 15;
#pragma unroll
  for (int i = 0; i < 4; i++) {
    int r = row + 16 * i;
    float4 v = *(const float4*)(in + (long)(r0 + r) * C + c0 + cg * 4);
    tl[r][cg * 4 + 0] = v.x; tl[r][cg * 4 + 1] = v.y;
    tl[r][cg * 4 + 2] = v.z; tl[r][cg * 4 + 3] = v.w;
  }
  __syncthreads();
#pragma unroll
  for (int i = 0; i < 4; i++) {
    int oc = row + 16 * i;
    ushort4 o;
    o.x = f2bf(tl[cg * 4 + 0][oc]);
    o.y = f2bf(tl[cg * 4 + 1][oc]);
    o.z = f2bf(tl[cg * 4 + 2][oc]);
    o.w = f2bf(tl[cg * 4 + 3][oc]);
    *(ushort4*)(out + (long)(c0 + oc) * R + r0 + cg * 4) = o;
  }
}

// ---------------- GEMM1: h[e] = relu(gather(xb) @ W1[e] + b1[e]) ----------------
// 128x128 tiles, BK=64, global_load_lds staging with pre-swizzled sources.
__global__ __launch_bounds__(256) void gemm1_kernel(
    const unsigned short* __restrict__ xb, const int* __restrict__ buf,
    const int* __restrict__ cnt, const unsigned short* __restrict__ wt1, long wtStride,
    const float* __restrict__ b1, const float* __restrict__ ob1,
    unsigned short* __restrict__ h, long hStride, int eBase,
    const unsigned short* __restrict__ zp) {
  int q = gridDim.x >> 3;
  int bx = blockIdx.x;
  int id = (bx & 7) * q + (bx >> 3);          // bijective XCD swizzle
  int e = eBase + (id >> 9);
  int rem = id & 511;
  int mb = rem >> 5, nb = rem & 31;
  int m0 = mb * 128, n0 = nb * 128;
  if (m0 >= cnt[e]) return;
  const int* bufe = buf + e * CAPACITY;
  int slot = e < 8 ? e : 8;
  const unsigned short* wte = wt1 + (long)slot * wtStride;
  const float* bias = (e < 8) ? b1 + (long)e * HDIM : ob1;
  unsigned short* he = h + (long)e * hStride;

  __shared__ unsigned short As[128 * 64];
  __shared__ unsigned short Bs[128 * 64];

  int tid = threadIdx.x;
  int wave = tid >> 6, lane = tid & 63;
  int l15 = lane & 15, hi = lane >> 4;
  int mo = (wave >> 1) * 64, no = (wave & 1) * 64;

  // Staging geometry: slice j covers rows wave*32+j*8 .. +7; lane's row offset
  // rlo = lane>>3, in-row chunk cl = lane&7, source chunk cg = cl ^ rlo
  // (involution: LDS[r][cl] = global[cl ^ (r&7)], matching the swizzled reads).
  int rlo = lane >> 3;
  int cg = (lane & 7) ^ rlo;
  const unsigned short* asrc[4];
  const unsigned short* bsrc[4];
#pragma unroll
  for (int j = 0; j < 4; j++) {
    int r = wave * 32 + j * 8 + rlo;
    int tok = bufe[m0 + r];
    asrc[j] = ((unsigned)tok < (unsigned)N_TOK) ? (xb + (long)tok * DMODEL + cg * 8)
                                                : (zp + cg * 8);
    bsrc[j] = wte + (long)(n0 + r) * DMODEL + cg * 8;
  }

  f32x4 zero4 = {0.f, 0.f, 0.f, 0.f};
  f32x4 acc[4][4];
#pragma unroll
  for (int mi = 0; mi < 4; mi++)
#pragma unroll
    for (int ni = 0; ni < 4; ni++) acc[mi][ni] = zero4;

  for (int k0 = 0; k0 < DMODEL; k0 += 64) {
#pragma unroll
    for (int j = 0; j < 4; j++) {
      gl_lds16(asrc[j] + k0, &As[wave * 2048 + j * 512]);
      gl_lds16(bsrc[j] + k0, &Bs[wave * 2048 + j * 512]);
    }
    __syncthreads();
#pragma unroll
    for (int ks = 0; ks < 2; ks++) {
      bf16x8 af[4], bfr[4];
#pragma unroll
      for (int mi = 0; mi < 4; mi++) {
        int r = mo + mi * 16 + l15;
        af[mi] = *(bf16x8*)&As[r * 64 + (((ks * 4 + hi) ^ (r & 7)) << 3)];
      }
#pragma unroll
      for (int ni = 0; ni < 4; ni++) {
        int r = no + ni * 16 + l15;
        bfr[ni] = *(bf16x8*)&Bs[r * 64 + (((ks * 4 + hi) ^ (r & 7)) << 3)];
      }
#pragma unroll
      for (int mi = 0; mi < 4; mi++)
#pragma unroll
        for (int ni = 0; ni < 4; ni++)
          acc[mi][ni] = __builtin_amdgcn_mfma_f32_16x16x32_bf16(af[mi], bfr[ni], acc[mi][ni], 0, 0, 0);
    }
    __syncthreads();
  }
#pragma unroll
  for (int ni = 0; ni < 4; ni++) {
    int col = n0 + no + ni * 16 + l15;
    float bv = bias[col];
#pragma unroll
    for (int mi = 0; mi < 4; mi++) {
#pragma unroll
      for (int j = 0; j < 4; j++) {
        int mr = m0 + mo + mi * 16 + hi * 4 + j;
        float val = acc[mi][ni][j] + bv;
        val = val > 0.f ? val : 0.f;
        he[(long)mr * HDIM + col] = f2bf(val);
      }
    }
  }
}

// ---------------- GEMM2: out[tok] += wc * (h[e] @ W2[e] + b2[e]) ----------------
__global__ __launch_bounds__(256) void gemm2_kernel(
    const unsigned short* __restrict__ h, long hStride,
    const unsigned short* __restrict__ wt2, long wtStride,
    const float* __restrict__ b2, const float* __restrict__ ob2,
    const int* __restrict__ buf, const float* __restrict__ wc,
    const int* __restrict__ cnt, float* __restrict__ out,
    int eBase, int per, int klen) {
  int q = gridDim.x >> 3;
  int bx = blockIdx.x;
  int id = (bx & 7) * q + (bx >> 3);          // bijective XCD swizzle
  int e = eBase + id / per;
  int rem = id % per;
  int tile = rem & 127;
  int kc = rem >> 7;
  int mb = tile >> 3, nb = tile & 7;
  int m0 = mb * 128, n0 = nb * 128;
  if (m0 >= cnt[e]) return;
  const int* bufe = buf + e * CAPACITY;
  const float* wce = wc + e * CAPACITY;
  int slot = e < 8 ? e : 8;
  const unsigned short* wte = wt2 + (long)slot * wtStride;
  const float* bias = (e < 8) ? b2 + (long)e * DMODEL : ob2;
  const unsigned short* he = h + (long)e * hStride;
  int kbase = kc * klen;

  __shared__ unsigned short As[128 * 64];
  __shared__ unsigned short Bs[128 * 64];

  int tid = threadIdx.x;
  int wave = tid >> 6, lane = tid & 63;
  int l15 = lane & 15, hi = lane >> 4;
  int mo = (wave >> 1) * 64, no = (wave & 1) * 64;

  int rlo = lane >> 3;
  int cg = (lane & 7) ^ rlo;
  const unsigned short* asrc[4];
  const unsigned short* bsrc[4];
#pragma unroll
  for (int j = 0; j < 4; j++) {
    int r = wave * 32 + j * 8 + rlo;
    asrc[j] = he + (long)(m0 + r) * HDIM + cg * 8;
    bsrc[j] = wte + (long)(n0 + r) * HDIM + cg * 8;
  }

  f32x4 zero4 = {0.f, 0.f, 0.f, 0.f};
  f32x4 acc[4][4];
#pragma unroll
  for (int mi = 0; mi < 4; mi++)
#pragma unroll
    for (int ni = 0; ni < 4; ni++) acc[mi][ni] = zero4;

  for (int k0 = kbase; k0 < kbase + klen; k0 += 64) {
#pragma unroll
    for (int j = 0; j < 4; j++) {
      gl_lds16(asrc[j] + k0, &As[wave * 2048 + j * 512]);
      gl_lds16(bsrc[j] + k0, &Bs[wave * 2048 + j * 512]);
    }
    __syncthreads();
#pragma unroll
    for (int ks = 0; ks < 2; ks++) {
      bf16x8 af[4], bfr[4];
#pragma unroll
      for (int mi = 0; mi < 4; mi++) {
        int r = mo + mi * 16 + l15;
        af[mi] = *(bf16x8*)&As[r * 64 + (((ks * 4 + hi) ^ (r & 7)) << 3)];
      }
#pragma unroll
      for (int ni = 0; ni < 4; ni++) {
        int r = no + ni * 16 + l15;
        bfr[ni] = *(bf16x8*)&Bs[r * 64 + (((ks * 4 + hi) ^ (r & 7)) << 3)];
      }
#pragma unroll
      for (int mi = 0; mi < 4; mi++)
#pragma unroll
        for (int ni = 0; ni < 4; ni++)
          acc[mi][ni] = __builtin_amdgcn_mfma_f32_16x16x32_bf16(af[mi], bfr[ni], acc[mi][ni], 0, 0, 0);
    }
    __syncthreads();
  }
  float bcol[4];
#pragma unroll
  for (int ni = 0; ni < 4; ni++)
    bcol[ni] = (kc == 0) ? bias[n0 + no + ni * 16 + l15] : 0.f;
#pragma unroll
  for (int mi = 0; mi < 4; mi++) {
#pragma unroll
    for (int j = 0; j < 4; j++) {
      int m = m0 + mo + mi * 16 + hi * 4 + j;
      int t = bufe[m];
      if ((unsigned)t >= (unsigned)N_TOK) continue;
      float wv = wce[m];
      float* orow = out + (long)t * DMODEL;
#pragma unroll
      for (int ni = 0; ni < 4; ni++) {
        int col = n0 + no + ni * 16 + l15;
        float val = wv * (acc[mi][ni][j] + bcol[ni]);
        atomicAdd(orow + col, val);
      }
    }
  }
}

// ---------------- host ----------------
extern "C" void kernel_launch(void* const* d_in, const int* in_sizes, int n_in,
                              void* d_out, int out_size, void* d_ws, size_t ws_size,
                              hipStream_t stream) {
  const float* x   = (const float*)d_in[0];
  const float* rw  = (const float*)d_in[1];
  const float* rb  = (const float*)d_in[2];
  const float* w1  = (const float*)d_in[3];
  const float* b1  = (const float*)d_in[4];
  const float* w2  = (const float*)d_in[5];
  const float* b2  = (const float*)d_in[6];
  const float* ow1 = (const float*)d_in[7];
  const float* ob1 = (const float*)d_in[8];
  const float* ow2 = (const float*)d_in[9];
  const float* ob2 = (const float*)d_in[10];
  float* out = (float*)d_out;

  const long WSLOT = (long)DMODEL * HDIM;      // 8 MB bf16 per weight slot
  const long HSLOT = (long)CAPACITY * HDIM;    // 16 MB bf16 per h slot

  bool fused = ws_size >= 380ull * 1024 * 1024;  // known: ws = 512 MB

  char* ws = (char*)d_ws;
  int4* recs = (int4*)(ws);
  int*  buf  = (int*)(ws + 131072);
  float* wcp = (float*)(ws + 229376);
  int*  cnt  = (int*)(ws + 327680);
  unsigned short* zp = (unsigned short*)(ws + 331776);      // 2 KB zero page
  unsigned short* xb  = (unsigned short*)(ws + 1048576);    // 16 MB
  unsigned short* wt1 = (unsigned short*)(ws + 17825792);
  unsigned short* wt2;
  unsigned short* h;
  if (fused) {
    wt2 = (unsigned short*)(ws + 93323264);    // wt1 + 9*8MB
    h   = (unsigned short*)(ws + 168820736);   // wt2 + 9*8MB
  } else {
    wt2 = (unsigned short*)(ws + 26214400);
    h   = (unsigned short*)(ws + 34603008);
  }

  hipMemsetAsync(d_out, 0, (size_t)out_size * sizeof(float), stream);
  hipMemsetAsync(buf, 0xFF, 12 * CAPACITY * sizeof(int), stream);
  hipMemsetAsync(wcp, 0, 12 * CAPACITY * sizeof(float), stream);
  hipMemsetAsync(zp, 0, 2048, stream);

  cvtx_kernel<<<2048, 256, 0, stream>>>(x, xb);
  router_kernel<<<2048, 256, 0, stream>>>(x, rw, rb, recs);
  assign_kernel<<<1, 1024, 0, stream>>>(recs, buf, wcp, cnt, out + (long)N_TOK * DMODEL);

  if (fused) {
    transpose_all<<<9 * 2048, 256, 0, stream>>>(w1, w2, ow1, ow2, wt1, wt2, WSLOT, 0);
    gemm1_kernel<<<12 * 512, 256, 0, stream>>>(xb, buf, cnt, wt1, WSLOT, b1, ob1, h, HSLOT, 0, zp);
    gemm2_kernel<<<12 * 128, 256, 0, stream>>>(h, HSLOT, wt2, WSLOT, b2, ob2, buf, wcp, cnt, out,
                                               0, 128, HDIM);
  } else {
    for (int e = 0; e < 12; e++) {
      if (e <= 8)
        transpose_all<<<2048, 256, 0, stream>>>(w1, w2, ow1, ow2, wt1, wt2, 0, e);
      gemm1_kernel<<<512, 256, 0, stream>>>(xb, buf, cnt, wt1, 0, b1, ob1, h, 0, e, zp);
      gemm2_kernel<<<512, 256, 0, stream>>>(h, 0, wt2, 0, b2, ob2, buf, wcp, cnt, out,
                                            e, 512, HDIM / 4);
    }
  }
}

// Round 6
// 654.120 us; speedup vs baseline: 1.4027x; 1.0475x over previous
//
#include <hip/hip_runtime.h>
#include <cstdint>

typedef __attribute__((ext_vector_type(8))) short bf16x8;
typedef __attribute__((ext_vector_type(4))) float f32x4;

#define N_TOK    8192
#define DMODEL   1024
#define HDIM     4096
#define CAPACITY 2048

__device__ __forceinline__ unsigned short f2bf(float f) {
  unsigned u = __float_as_uint(f);
  u += 0x7FFFu + ((u >> 16) & 1u);
  return (unsigned short)(u >> 16);
}

// global (16B/lane) -> LDS direct DMA; lds base must be wave-uniform.
__device__ __forceinline__ void gl_lds16(const unsigned short* g, unsigned short* l) {
  __builtin_amdgcn_global_load_lds(
      (const __attribute__((address_space(1))) void*)g,
      (__attribute__((address_space(3))) void*)l, 16, 0, 0);
}

// ---------------- x -> bf16 ----------------
__global__ void cvtx_kernel(const float* __restrict__ x, unsigned short* __restrict__ xb) {
  long i0 = ((long)blockIdx.x * 256 + threadIdx.x) * 16;
#pragma unroll
  for (int ii = 0; ii < 4; ii++) {
    float4 v = *(const float4*)(x + i0 + ii * 4);
    ushort4 u;
    u.x = f2bf(v.x); u.y = f2bf(v.y); u.z = f2bf(v.z); u.w = f2bf(v.w);
    *(ushort4*)(xb + i0 + ii * 4) = u;
  }
}

// ---------------- router: logits -> top2 ----------------
__global__ void router_kernel(const float* __restrict__ x, const float* __restrict__ rw,
                              const float* __restrict__ rb, int4* __restrict__ recs) {
  int wave = threadIdx.x >> 6;
  int lane = threadIdx.x & 63;
  int tok = blockIdx.x * 4 + wave;
  const float* xr = x + (long)tok * DMODEL;
  float s[8];
#pragma unroll
  for (int e = 0; e < 8; e++) s[e] = 0.f;
  for (int ii = 0; ii < DMODEL / 64; ii++) {
    int k = lane + 64 * ii;
    float xv = xr[k];
    const float* wr = rw + k * 8;
    float4 a = *(const float4*)wr;
    float4 b = *(const float4*)(wr + 4);
    s[0] += xv * a.x; s[1] += xv * a.y; s[2] += xv * a.z; s[3] += xv * a.w;
    s[4] += xv * b.x; s[5] += xv * b.y; s[6] += xv * b.z; s[7] += xv * b.w;
  }
#pragma unroll
  for (int m = 1; m < 64; m <<= 1) {
#pragma unroll
    for (int e = 0; e < 8; e++) s[e] += __shfl_xor(s[e], m);
  }
  if (lane == 0) {
#pragma unroll
    for (int e = 0; e < 8; e++) s[e] += rb[e];
    int b0 = 0; float v0 = s[0];
#pragma unroll
    for (int e = 1; e < 8; e++) if (s[e] > v0) { v0 = s[e]; b0 = e; }
    int b1 = -1; float v1 = 0.f;
#pragma unroll
    for (int e = 0; e < 8; e++) {
      if (e == b0) continue;
      if (b1 < 0 || s[e] > v1) { v1 = s[e]; b1 = e; }
    }
    float t0 = 1.f / (1.f + expf(v1 - v0));
    float t1 = 1.f - t0;
    recs[tok] = make_int4(b0, b1, __float_as_int(t0), __float_as_int(t1));
  }
}

// ---------------- capacity assignment (single block) ----------------
__device__ __forceinline__ int bump16(uint4& v, int e) {
  unsigned sh = (e & 1) ? 16u : 0u;
  unsigned inc = 1u << sh;
  unsigned old;
  switch (e >> 1) {
    case 0: old = v.x; v.x += inc; break;
    case 1: old = v.y; v.y += inc; break;
    case 2: old = v.z; v.z += inc; break;
    default: old = v.w; v.w += inc; break;
  }
  return (int)((old >> sh) & 0xFFFFu);
}

__device__ __forceinline__ unsigned field16(uint4 v, int e) {
  unsigned w;
  switch (e >> 1) { case 0: w = v.x; break; case 1: w = v.y; break; case 2: w = v.z; break; default: w = v.w; break; }
  return (w >> ((e & 1) ? 16 : 0)) & 0xFFFFu;
}

__global__ void assign_kernel(const int4* __restrict__ recs, int* __restrict__ buf,
                              float* __restrict__ wc, int* __restrict__ cnt,
                              float* __restrict__ auxOut) {
  __shared__ uint4 sc[1024];
  __shared__ unsigned sco[1024];
  __shared__ float pnum[8];
  int tid = threadIdx.x;
  if (tid < 8) pnum[tid] = 0.f;
  int4 rc[8];
#pragma unroll
  for (int i = 0; i < 8; i++) {
    rc[i] = recs[tid * 8 + i];
    rc[i].x &= 7; rc[i].y &= 7;
  }
  uint4 c; c.x = c.y = c.z = c.w = 0u;
#pragma unroll
  for (int i = 0; i < 8; i++) { bump16(c, rc[i].x); bump16(c, rc[i].y); }
  sc[tid] = c;
  __syncthreads();
  for (int off = 1; off < 1024; off <<= 1) {
    uint4 v; v.x = v.y = v.z = v.w = 0u;
    if (tid >= off) v = sc[tid - off];
    __syncthreads();
    sc[tid].x += v.x; sc[tid].y += v.y; sc[tid].z += v.z; sc[tid].w += v.w;
    __syncthreads();
  }
  uint4 base; base.x = base.y = base.z = base.w = 0u;
  if (tid > 0) base = sc[tid - 1];
  uint4 totals = sc[1023];

  uint4 run = base;
  float wof[8];
  unsigned oc = 0;
#pragma unroll
  for (int i = 0; i < 8; i++) {
    int tk = tid * 8 + i;
    int e0 = rc[i].x, e1 = rc[i].y;
    float w0 = __int_as_float(rc[i].z);
    float w1 = __int_as_float(rc[i].w);
    float w = 0.f;
    int r0 = bump16(run, e0);
    if (r0 < CAPACITY) {
      buf[e0 * CAPACITY + r0] = tk;
      wc[e0 * CAPACITY + r0] = w0;
      atomicAdd(&pnum[e0], w0);
    } else w += w0;
    int r1 = bump16(run, e1);
    if (r1 < CAPACITY) {
      buf[e1 * CAPACITY + r1] = tk;
      wc[e1 * CAPACITY + r1] = w1;
      atomicAdd(&pnum[e1], w1);
    } else w += w1;
    wof[i] = w;
    if (w > 0.f) oc++;
  }
  sco[tid] = oc;
  __syncthreads();
  for (int off = 1; off < 1024; off <<= 1) {
    unsigned v = (tid >= off) ? sco[tid - off] : 0u;
    __syncthreads();
    sco[tid] += v;
    __syncthreads();
  }
  unsigned ob = (tid > 0) ? sco[tid - 1] : 0u;
  unsigned Ot = sco[1023];
#pragma unroll
  for (int i = 0; i < 8; i++) {
    if (wof[i] > 0.f) {
      unsigned slot = ob++;
      int ve = 8 + (int)(slot >> 11);
      buf[ve * CAPACITY + (int)(slot & 2047)] = tid * 8 + i;
      wc[ve * CAPACITY + (int)(slot & 2047)] = wof[i];
    }
  }
  __syncthreads();
  if (tid == 0) {
    float aux = 0.f;
#pragma unroll
    for (int e = 0; e < 8; e++) {
      int tot = (int)field16(totals, e);
      int c2 = tot < CAPACITY ? tot : CAPACITY;
      cnt[e] = c2;
      float f = (float)c2 / (float)N_TOK;
      float p = pnum[e] / (float)(c2 > 1 ? c2 : 1);
      aux += f * p;
    }
#pragma unroll
    for (int i = 0; i < 4; i++) {
      int c2 = (int)Ot - i * CAPACITY;
      c2 = c2 < 0 ? 0 : (c2 > CAPACITY ? CAPACITY : c2);
      cnt[8 + i] = c2;
    }
    auxOut[0] = 0.01f * 8.f * aux;
  }
}

// ---------------- fp32 -> bf16 transpose of weight pairs ----------------
__global__ __launch_bounds__(256) void transpose_all(
    const float* __restrict__ w1, const float* __restrict__ w2,
    const float* __restrict__ ow1, const float* __restrict__ ow2,
    unsigned short* __restrict__ wt1, unsigned short* __restrict__ wt2,
    long slotStride, int pairBase) {
  int pair = pairBase + blockIdx.x / 2048;
  int t = blockIdx.x & 2047;
  long srcOff = (long)pair * DMODEL * HDIM;
  long dstOff = (long)(blockIdx.x / 2048) * slotStride;
  const float* in; unsigned short* out; int R, C;
  if (t < 1024) {
    in = (pair < 8) ? w1 + srcOff : ow1;
    out = wt1 + dstOff;
    R = DMODEL; C = HDIM;
  } else {
    in = (pair < 8) ? w2 + srcOff : ow2;
    out = wt2 + dstOff;
    R = HDIM; C = DMODEL;
    t -= 1024;
  }
  int tr = t / (C >> 6);
  int tc = t % (C >> 6);
  int r0 = tr << 6, c0 = tc << 6;
  __shared__ float tl[64][65];
  int row = threadIdx.x >> 4, cg = threadIdx.x & 15;
#pragma unroll
  for (int i = 0; i < 4; i++) {
    int r = row + 16 * i;
    float4 v = *(const float4*)(in + (long)(r0 + r) * C + c0 + cg * 4);
    tl[r][cg * 4 + 0] = v.x; tl[r][cg * 4 + 1] = v.y;
    tl[r][cg * 4 + 2] = v.z; tl[r][cg * 4 + 3] = v.w;
  }
  __syncthreads();
#pragma unroll
  for (int i = 0; i < 4; i++) {
    int oc = row + 16 * i;
    ushort4 o;
    o.x = f2bf(tl[cg * 4 + 0][oc]);
    o.y = f2bf(tl[cg * 4 + 1][oc]);
    o.z = f2bf(tl[cg * 4 + 2][oc]);
    o.w = f2bf(tl[cg * 4 + 3][oc]);
    *(ushort4*)(out + (long)(c0 + oc) * R + r0 + cg * 4) = o;
  }
}

// ==================== 256x256-tile 2-phase GEMMs ====================
// 512 threads = 8 waves (2 M x 4 N); per-wave output 128x64.
// LDS: double-buffered A,B 256x64 bf16 each = 128 KB.
// Staging: wave w stages rows [w*32, w*32+32) via 4 slices of 8 rows;
// lane: rlo=lane>>3 row-in-slice, source chunk cg=(lane&7)^rlo so that
// LDS[r][cl] = global chunk cl^(r&7)  (XOR involution, matches reads).

#define STAGE_PAIR(Abuf, Bbuf, kk)                                  \
  do {                                                              \
    _Pragma("unroll") for (int s = 0; s < 4; s++) {                 \
      gl_lds16(asrc[s] + (kk), &(Abuf)[wave * 2048 + s * 512]);     \
      gl_lds16(bsrc[s] + (kk), &(Bbuf)[wave * 2048 + s * 512]);     \
    }                                                               \
  } while (0)

// ---------------- GEMM1: h[e] = relu(gather(xb) @ W1[e] + b1[e]) ----------------
// grid = nE * 128 (8 mb x 16 nb)
__global__ __launch_bounds__(512, 2) void gemm1_kernel(
    const unsigned short* __restrict__ xb, const int* __restrict__ buf,
    const int* __restrict__ cnt, const unsigned short* __restrict__ wt1, long wtStride,
    const float* __restrict__ b1, const float* __restrict__ ob1,
    unsigned short* __restrict__ h, long hStride, int eBase,
    const unsigned short* __restrict__ zp) {
  int q = gridDim.x >> 3;
  int bx = blockIdx.x;
  int id = (bx & 7) * q + (bx >> 3);          // bijective XCD swizzle
  int e = eBase + id / 128;
  int rem = id % 128;
  int mb = rem >> 4, nb = rem & 15;
  int m0 = mb * 256, n0 = nb * 256;
  if (m0 >= cnt[e]) return;
  const int* bufe = buf + e * CAPACITY;
  int slot = e < 8 ? e : 8;
  const unsigned short* wte = wt1 + (long)slot * wtStride;
  const float* bias = (e < 8) ? b1 + (long)e * HDIM : ob1;
  unsigned short* he = h + (long)e * hStride;

  __shared__ unsigned short As[2][256 * 64];
  __shared__ unsigned short Bs[2][256 * 64];

  int tid = threadIdx.x;
  int wave = tid >> 6, lane = tid & 63;
  int l15 = lane & 15, hi = lane >> 4;
  int wr = wave >> 2, wc = wave & 3;
  int mo = wr * 128, no = wc * 64;

  int rlo = lane >> 3;
  int cg = (lane & 7) ^ rlo;
  const unsigned short* asrc[4];
  const unsigned short* bsrc[4];
#pragma unroll
  for (int s = 0; s < 4; s++) {
    int r = wave * 32 + s * 8 + rlo;
    int tok = bufe[m0 + r];
    asrc[s] = ((unsigned)tok < (unsigned)N_TOK) ? (xb + (long)tok * DMODEL + cg * 8)
                                                : (zp + cg * 8);
    bsrc[s] = wte + (long)(n0 + r) * DMODEL + cg * 8;
  }

  f32x4 zero4 = {0.f, 0.f, 0.f, 0.f};
  f32x4 acc[8][4];
#pragma unroll
  for (int mi = 0; mi < 8; mi++)
#pragma unroll
    for (int ni = 0; ni < 4; ni++) acc[mi][ni] = zero4;

  const int NT = DMODEL / 64;
  STAGE_PAIR(As[0], Bs[0], 0);
  __syncthreads();                 // compiler drains vmcnt(0) before barrier
  int cur = 0;
  for (int t = 0; t < NT; t++) {
    if (t + 1 < NT) {
      if (cur) STAGE_PAIR(As[0], Bs[0], (t + 1) * 64);
      else     STAGE_PAIR(As[1], Bs[1], (t + 1) * 64);
    }
    const unsigned short* Ac = As[cur];
    const unsigned short* Bc = Bs[cur];
#pragma unroll
    for (int ks = 0; ks < 2; ks++) {
      bf16x8 af[8], bfv[4];
#pragma unroll
      for (int mi = 0; mi < 8; mi++) {
        int r = mo + mi * 16 + l15;
        af[mi] = *(bf16x8*)&Ac[r * 64 + (((ks * 4 + hi) ^ (r & 7)) << 3)];
      }
#pragma unroll
      for (int ni = 0; ni < 4; ni++) {
        int r = no + ni * 16 + l15;
        bfv[ni] = *(bf16x8*)&Bc[r * 64 + (((ks * 4 + hi) ^ (r & 7)) << 3)];
      }
#pragma unroll
      for (int mi = 0; mi < 8; mi++)
#pragma unroll
        for (int ni = 0; ni < 4; ni++)
          acc[mi][ni] = __builtin_amdgcn_mfma_f32_16x16x32_bf16(af[mi], bfv[ni], acc[mi][ni], 0, 0, 0);
    }
    __syncthreads();               // drains next-tile stage + LDS reads
    cur ^= 1;
  }
#pragma unroll
  for (int ni = 0; ni < 4; ni++) {
    int col = n0 + no + ni * 16 + l15;
    float bv = bias[col];
#pragma unroll
    for (int mi = 0; mi < 8; mi++) {
#pragma unroll
      for (int j = 0; j < 4; j++) {
        int mr = m0 + mo + mi * 16 + hi * 4 + j;
        float val = acc[mi][ni][j] + bv;
        val = val > 0.f ? val : 0.f;
        he[(long)mr * HDIM + col] = f2bf(val);
      }
    }
  }
}

// ---------------- GEMM2: out[tok] += wc * (h[e] @ W2[e] + b2[e]) ----------------
// grid = nE * 64 (8 mb x 4 nb x 2 kc), klen = 2048
__global__ __launch_bounds__(512, 2) void gemm2_kernel(
    const unsigned short* __restrict__ h, long hStride,
    const unsigned short* __restrict__ wt2, long wtStride,
    const float* __restrict__ b2, const float* __restrict__ ob2,
    const int* __restrict__ buf, const float* __restrict__ wc,
    const int* __restrict__ cnt, float* __restrict__ out,
    int eBase, int per, int klen) {
  int q = gridDim.x >> 3;
  int bx = blockIdx.x;
  int id = (bx & 7) * q + (bx >> 3);
  int e = eBase + id / per;
  int rem = id % per;
  int tile = rem & 31;
  int kc = rem >> 5;
  int mb = tile >> 2, nb = tile & 3;
  int m0 = mb * 256, n0 = nb * 256;
  if (m0 >= cnt[e]) return;
  const int* bufe = buf + e * CAPACITY;
  const float* wce = wc + e * CAPACITY;
  int slot = e < 8 ? e : 8;
  const unsigned short* wte = wt2 + (long)slot * wtStride;
  const float* bias = (e < 8) ? b2 + (long)e * DMODEL : ob2;
  const unsigned short* he = h + (long)e * hStride;
  int kbase = kc * klen;

  __shared__ unsigned short As[2][256 * 64];
  __shared__ unsigned short Bs[2][256 * 64];

  int tid = threadIdx.x;
  int wave = tid >> 6, lane = tid & 63;
  int l15 = lane & 15, hi = lane >> 4;
  int wr = wave >> 2, wc2 = wave & 3;
  int mo = wr * 128, no = wc2 * 64;

  int rlo = lane >> 3;
  int cg = (lane & 7) ^ rlo;
  const unsigned short* asrc[4];
  const unsigned short* bsrc[4];
#pragma unroll
  for (int s = 0; s < 4; s++) {
    int r = wave * 32 + s * 8 + rlo;
    asrc[s] = he + (long)(m0 + r) * HDIM + kbase + cg * 8;
    bsrc[s] = wte + (long)(n0 + r) * HDIM + kbase + cg * 8;
  }

  f32x4 zero4 = {0.f, 0.f, 0.f, 0.f};
  f32x4 acc[8][4];
#pragma unroll
  for (int mi = 0; mi < 8; mi++)
#pragma unroll
    for (int ni = 0; ni < 4; ni++) acc[mi][ni] = zero4;

  const int NT = klen / 64;
  STAGE_PAIR(As[0], Bs[0], 0);
  __syncthreads();
  int cur = 0;
  for (int t = 0; t < NT; t++) {
    if (t + 1 < NT) {
      if (cur) STAGE_PAIR(As[0], Bs[0], (t + 1) * 64);
      else     STAGE_PAIR(As[1], Bs[1], (t + 1) * 64);
    }
    const unsigned short* Ac = As[cur];
    const unsigned short* Bc = Bs[cur];
#pragma unroll
    for (int ks = 0; ks < 2; ks++) {
      bf16x8 af[8], bfv[4];
#pragma unroll
      for (int mi = 0; mi < 8; mi++) {
        int r = mo + mi * 16 + l15;
        af[mi] = *(bf16x8*)&Ac[r * 64 + (((ks * 4 + hi) ^ (r & 7)) << 3)];
      }
#pragma unroll
      for (int ni = 0; ni < 4; ni++) {
        int r = no + ni * 16 + l15;
        bfv[ni] = *(bf16x8*)&Bc[r * 64 + (((ks * 4 + hi) ^ (r & 7)) << 3)];
      }
#pragma unroll
      for (int mi = 0; mi < 8; mi++)
#pragma unroll
        for (int ni = 0; ni < 4; ni++)
          acc[mi][ni] = __builtin_amdgcn_mfma_f32_16x16x32_bf16(af[mi], bfv[ni], acc[mi][ni], 0, 0, 0);
    }
    __syncthreads();
    cur ^= 1;
  }
  float bcol[4];
#pragma unroll
  for (int ni = 0; ni < 4; ni++)
    bcol[ni] = (kc == 0) ? bias[n0 + no + ni * 16 + l15] : 0.f;
#pragma unroll
  for (int mi = 0; mi < 8; mi++) {
#pragma unroll
    for (int j = 0; j < 4; j++) {
      int m = m0 + mo + mi * 16 + hi * 4 + j;
      int t = bufe[m];
      if ((unsigned)t >= (unsigned)N_TOK) continue;
      float wv = wce[m];
      float* orow = out + (long)t * DMODEL;
#pragma unroll
      for (int ni = 0; ni < 4; ni++) {
        int col = n0 + no + ni * 16 + l15;
        float val = wv * (acc[mi][ni][j] + bcol[ni]);
        atomicAdd(orow + col, val);
      }
    }
  }
}

// ---------------- host ----------------
extern "C" void kernel_launch(void* const* d_in, const int* in_sizes, int n_in,
                              void* d_out, int out_size, void* d_ws, size_t ws_size,
                              hipStream_t stream) {
  const float* x   = (const float*)d_in[0];
  const float* rw  = (const float*)d_in[1];
  const float* rb  = (const float*)d_in[2];
  const float* w1  = (const float*)d_in[3];
  const float* b1  = (const float*)d_in[4];
  const float* w2  = (const float*)d_in[5];
  const float* b2  = (const float*)d_in[6];
  const float* ow1 = (const float*)d_in[7];
  const float* ob1 = (const float*)d_in[8];
  const float* ow2 = (const float*)d_in[9];
  const float* ob2 = (const float*)d_in[10];
  float* out = (float*)d_out;

  const long WSLOT = (long)DMODEL * HDIM;      // 8 MB bf16 per weight slot
  const long HSLOT = (long)CAPACITY * HDIM;    // 16 MB bf16 per h slot

  bool fused = ws_size >= 380ull * 1024 * 1024;  // known: ws = 512 MB

  char* ws = (char*)d_ws;
  int4* recs = (int4*)(ws);
  int*  buf  = (int*)(ws + 131072);
  float* wcp = (float*)(ws + 229376);
  int*  cnt  = (int*)(ws + 327680);
  unsigned short* zp = (unsigned short*)(ws + 331776);      // 2 KB zero page
  unsigned short* xb  = (unsigned short*)(ws + 1048576);    // 16 MB
  unsigned short* wt1 = (unsigned short*)(ws + 17825792);
  unsigned short* wt2;
  unsigned short* h;
  if (fused) {
    wt2 = (unsigned short*)(ws + 93323264);    // wt1 + 9*8MB
    h   = (unsigned short*)(ws + 168820736);   // wt2 + 9*8MB
  } else {
    wt2 = (unsigned short*)(ws + 26214400);
    h   = (unsigned short*)(ws + 34603008);
  }

  hipMemsetAsync(d_out, 0, (size_t)out_size * sizeof(float), stream);
  hipMemsetAsync(buf, 0xFF, 12 * CAPACITY * sizeof(int), stream);
  hipMemsetAsync(wcp, 0, 12 * CAPACITY * sizeof(float), stream);
  hipMemsetAsync(zp, 0, 2048, stream);

  cvtx_kernel<<<2048, 256, 0, stream>>>(x, xb);
  router_kernel<<<2048, 256, 0, stream>>>(x, rw, rb, recs);
  assign_kernel<<<1, 1024, 0, stream>>>(recs, buf, wcp, cnt, out + (long)N_TOK * DMODEL);

  if (fused) {
    transpose_all<<<9 * 2048, 256, 0, stream>>>(w1, w2, ow1, ow2, wt1, wt2, WSLOT, 0);
    gemm1_kernel<<<12 * 128, 512, 0, stream>>>(xb, buf, cnt, wt1, WSLOT, b1, ob1, h, HSLOT, 0, zp);
    gemm2_kernel<<<12 * 64, 512, 0, stream>>>(h, HSLOT, wt2, WSLOT, b2, ob2, buf, wcp, cnt, out,
                                              0, 64, HDIM / 2);
  } else {
    for (int e = 0; e < 12; e++) {
      if (e <= 8)
        transpose_all<<<2048, 256, 0, stream>>>(w1, w2, ow1, ow2, wt1, wt2, 0, e);
      gemm1_kernel<<<128, 512, 0, stream>>>(xb, buf, cnt, wt1, 0, b1, ob1, h, 0, e, zp);
      gemm2_kernel<<<64, 512, 0, stream>>>(h, 0, wt2, 0, b2, ob2, buf, wcp, cnt, out,
                                           e, 64, HDIM / 2);
    }
  }
}